// Round 8
// baseline (134.905 us; speedup 1.0000x reference)
//
#include <hip/hip_runtime.h>
#include <hip/hip_bf16.h>

// ROIAlign: feat [B=4, C=256, H=200, W=304] fp32, rois [N=1024,4] fp32,
// roibatches [N] int32 -> out [N, C, 7, 7] fp32.  POOL=7, SCALE=0.25, SAMP=2.
//
// K0: sort roi ids by (batch, y-center) -> perm (1 block, ballot count-sort).
// K1: NCHW fp32 -> NHWC bf16 (d_ws, 124 MB). ~HBM BW floor.
// K2: one block (512 thr) per roi (XCD-chunked rank mapping); ONE bin per
//     wave. Pair-loads: lane uint4 (16B) so one 1KB wave-load covers BOTH
//     x corners (lanes 0-31 = x_lo, 32-63 = x_hi, 8 ch each); halves combine
//     via __shfl_xor(acc,32). 8 loads/bin instead of 16.

#define POOL 7
constexpr int Bc = 4;
constexpr int Cc = 256;
constexpr int Hc = 200;
constexpr int Wc = 304;
constexpr int HWc = Hc * Wc;           // 60800
constexpr float SCALEc = 0.25f;
constexpr int STR = 132;               // LDS row stride in u32 (128 + 4 pad, 16B-aligned)

static __device__ __forceinline__ float bf16_lo(unsigned u) {
    u <<= 16;
    return __builtin_bit_cast(float, u);
}
static __device__ __forceinline__ float bf16_hi(unsigned u) {
    u &= 0xFFFF0000u;
    return __builtin_bit_cast(float, u);
}
static __device__ __forceinline__ unsigned pack_bf16(float f0, float f1) {
    unsigned u0 = (unsigned)__hip_bfloat16_raw(__float2bfloat16(f0)).x;
    unsigned u1 = (unsigned)__hip_bfloat16_raw(__float2bfloat16(f1)).x;
    return u0 | (u1 << 16);
}

// ---------------- K0: stable counting sort by (batch, y-bucket) ----------------
__global__ __launch_bounds__(1024) void sort_rois(
    const float* __restrict__ rois, const int* __restrict__ rb,
    int* __restrict__ perm, int N)
{
    __shared__ int wave_cnt[16][32];
    __shared__ int bucket_base[32];
    int t    = threadIdx.x;
    int w    = t >> 6;
    int lane = t & 63;

    int key = -1;
    if (t < N) {
        int b = rb[t];
        float yc = (rois[t * 4 + 1] + rois[t * 4 + 3]) * 0.5f * SCALEc;  // 0..~200
        int bucket = min(max((int)(yc * (8.0f / 200.0f)), 0), 7);
        key = b * 8 + bucket;
    }
    unsigned long long lt = (lane == 0) ? 0ULL : (~0ULL >> (64 - lane));
    int rank_in_wave = 0;
#pragma unroll 1
    for (int k = 0; k < 32; ++k) {
        unsigned long long m = __ballot(key == k);
        if (lane == 0) wave_cnt[w][k] = __popcll(m);
        if (key == k)  rank_in_wave = __popcll(m & lt);
    }
    __syncthreads();
    if (t == 0) {
        int base = 0;
        for (int k = 0; k < 32; ++k) {
            int tot = 0;
            for (int ww = 0; ww < 16; ++ww) tot += wave_cnt[ww][k];
            bucket_base[k] = base;
            base += tot;
        }
    }
    __syncthreads();
    if (key >= 0) {
        int rank = bucket_base[key] + rank_in_wave;
        for (int ww = 0; ww < w; ++ww) rank += wave_cnt[ww][key];
        perm[rank] = t;
    }
}

// ---------------- K1: NCHW fp32 -> NHWC bf16 ----------------
__global__ __launch_bounds__(256) void nchw_to_nhwc_bf16(
    const float* __restrict__ in, ushort* __restrict__ outp)
{
    __shared__ float tile[128][65];
    int b  = blockIdx.z;
    int p0 = blockIdx.x * 64;    // HW origin
    int c0 = blockIdx.y * 128;   // C origin
    int tx = threadIdx.x;        // 0..63
    int ty = threadIdx.y;        // 0..3

    const float* src = in + ((size_t)b * Cc + c0) * (size_t)HWc + p0;
#pragma unroll
    for (int k = 0; k < 32; ++k) {
        int c = ty + 4 * k;
        tile[c][tx ^ ((c >> 5) & 3)] = src[(size_t)c * HWc + tx];
    }
    __syncthreads();

    int t  = ty * 64 + tx;       // 0..255
    int cg = t & 15;             // 8-channel group
    int pi = t >> 4;             // 0..15
#pragma unroll
    for (int k = 0; k < 4; ++k) {
        int p = pi + 16 * k;     // 0..63
        unsigned u[4];
#pragma unroll
        for (int j = 0; j < 4; ++j) {
            int ce = cg * 8 + 2 * j;
            int co = ce + 1;
            float f0 = tile[ce][p ^ ((ce >> 5) & 3)];
            float f1 = tile[co][p ^ ((co >> 5) & 3)];
            u[j] = pack_bf16(f0, f1);
        }
        size_t d = ((size_t)b * HWc + p0 + p) * (size_t)Cc + c0 + cg * 8;
        *(uint4*)(outp + d) = make_uint4(u[0], u[1], u[2], u[3]);
    }
}

// ---------------- K2: gather + pool ----------------
__global__ __launch_bounds__(512, 8) void roialign_gather(
    const ushort* __restrict__ f,      // NHWC bf16
    const float*  __restrict__ rois,
    const int*    __restrict__ rb,
    const int*    __restrict__ perm,
    float*        __restrict__ out)
{
    __shared__ unsigned stage[49 * STR];  // packed bf16 pairs, [bin][c/2]

    // XCD-chunked rank mapping: XCD k gets contiguous sorted ranks
    int bid = blockIdx.x;
    int r   = bid;
    if ((gridDim.x & 7) == 0) {
        int per = gridDim.x >> 3;
        r = (bid & 7) * per + (bid >> 3);
    }
    int n    = perm[r];
    int t    = threadIdx.x;   // 0..511
    int wav  = t >> 6;        // 0..7  -> bin = it*8 + wav
    int lane = t & 63;
    int half = lane >> 5;     // 0: x_lo-half, 1: x_hi-half
    int sub  = lane & 31;     // channels sub*8 .. sub*8+7

    float x1 = rois[n * 4 + 0] * SCALEc;
    float y1 = rois[n * 4 + 1] * SCALEc;
    float x2 = rois[n * 4 + 2] * SCALEc;
    float y2 = rois[n * 4 + 3] * SCALEc;
    int   b  = rb[n];

    float roi_w = fmaxf(x2 - x1, 1.0f);
    float roi_h = fmaxf(y2 - y1, 1.0f);
    float bin_w = roi_w * (1.0f / POOL);
    float bin_h = roi_h * (1.0f / POOL);

    // uint4 view: one pixel = 32 uint4 (256 bf16 ch); wave-load of
    // fb4[(pix)*32 + lane] covers pixels pix (lanes 0-31) and pix+1 (32-63).
    const uint4* fb4 = (const uint4*)(f + (size_t)b * ((size_t)HWc * Cc));

#pragma unroll 1
    for (int it = 0; it < 7; ++it) {
        int bin = it * 8 + wav;            // 0..55
        if (bin < 49) {
            int ph = (bin * 9363) >> 16;   // bin / 7
            int pw = bin - ph * 7;

            unsigned yrow[2][2];  float wy[2][2];
#pragma unroll
            for (int iy = 0; iy < 2; ++iy) {
                float y  = y1 + ((float)ph + ((float)iy + 0.5f) * 0.5f) * bin_h;
                bool  vy = (y >= -1.0f) && (y <= (float)Hc);
                float yc = fminf(fmaxf(y, 0.0f), (float)(Hc - 1));
                int   y_lo = (int)floorf(yc);
                int   y_hi = min(y_lo + 1, Hc - 1);
                float ly = yc - (float)y_lo;
                yrow[iy][0] = (unsigned)(y_lo * Wc);
                yrow[iy][1] = (unsigned)(y_hi * Wc);
                wy[iy][0] = vy ? (1.0f - ly) : 0.0f;
                wy[iy][1] = vy ? ly : 0.0f;
            }
            // x-pair bases + per-half weights (handles x_hi clamp at W-1)
            unsigned xb[2];  float wxh[2];
#pragma unroll
            for (int ix = 0; ix < 2; ++ix) {
                float x  = x1 + ((float)pw + ((float)ix + 0.5f) * 0.5f) * bin_w;
                bool  vx = (x >= -1.0f) && (x <= (float)Wc);
                float xc = fminf(fmaxf(x, 0.0f), (float)(Wc - 1));
                int   x_lo = (int)floorf(xc);
                int   x_hi = min(x_lo + 1, Wc - 1);
                float lx = xc - (float)x_lo;
                float wx0 = vx ? (1.0f - lx) : 0.0f;   // weight of x_lo
                float wx1 = vx ? lx : 0.0f;            // weight of x_hi
                int   bx  = min(x_lo, Wc - 2);         // pair base (bx, bx+1)
                int   off_lo = x_lo - bx;              // 0 or 1
                int   off_hi = x_hi - bx;              // 1 (or 1 when clamped)
                float w0 = (off_lo == 0 ? wx0 : 0.0f) + (off_hi == 0 ? wx1 : 0.0f);
                float w1 = (off_lo == 1 ? wx0 : 0.0f) + (off_hi == 1 ? wx1 : 0.0f);
                xb[ix]  = (unsigned)bx;
                wxh[ix] = half ? w1 : w0;
            }

            float acc[8] = {0.f, 0.f, 0.f, 0.f, 0.f, 0.f, 0.f, 0.f};
#pragma unroll
            for (int iy = 0; iy < 2; ++iy) {
                // 4 pair-loads (2 y-corners x 2 x-samples), 1KB each
                uint4 v[4];
#pragma unroll
                for (int q = 0; q < 4; ++q) {
                    int yl = q >> 1, ix = q & 1;
                    unsigned pix = yrow[iy][yl] + xb[ix];
                    v[q] = fb4[(size_t)(pix * 32u + (unsigned)lane)];
                }
#pragma unroll
                for (int q = 0; q < 4; ++q) {
                    int yl = q >> 1, ix = q & 1;
                    float w = wy[iy][yl] * wxh[ix];
                    acc[0] = fmaf(w, bf16_lo(v[q].x), acc[0]);
                    acc[1] = fmaf(w, bf16_hi(v[q].x), acc[1]);
                    acc[2] = fmaf(w, bf16_lo(v[q].y), acc[2]);
                    acc[3] = fmaf(w, bf16_hi(v[q].y), acc[3]);
                    acc[4] = fmaf(w, bf16_lo(v[q].z), acc[4]);
                    acc[5] = fmaf(w, bf16_hi(v[q].z), acc[5]);
                    acc[6] = fmaf(w, bf16_lo(v[q].w), acc[6]);
                    acc[7] = fmaf(w, bf16_hi(v[q].w), acc[7]);
                }
            }
            // combine x_lo-half and x_hi-half
#pragma unroll
            for (int j = 0; j < 8; ++j) acc[j] += __shfl_xor(acc[j], 32);

            if (half == 0) {
                unsigned p0 = pack_bf16(acc[0] * 0.25f, acc[1] * 0.25f);
                unsigned p1 = pack_bf16(acc[2] * 0.25f, acc[3] * 0.25f);
                unsigned p2 = pack_bf16(acc[4] * 0.25f, acc[5] * 0.25f);
                unsigned p3 = pack_bf16(acc[6] * 0.25f, acc[7] * 0.25f);
                *(uint4*)&stage[bin * STR + sub * 4] = make_uint4(p0, p1, p2, p3);
            }
        }
    }
    __syncthreads();

    // coalesced write of this roi's 12544-float chunk, flat = c*49 + bin
    float* obase = out + (size_t)n * (Cc * POOL * POOL);
#pragma unroll 1
    for (int k = 0; k < 25; ++k) {
        int flat = t + 512 * k;
        if (flat < Cc * POOL * POOL) {
            unsigned c   = ((unsigned)flat * 42800u) >> 21;   // flat / 49
            unsigned bin = (unsigned)flat - c * 49u;
            unsigned u   = stage[bin * STR + (c >> 1)];
            obase[flat]  = (c & 1) ? bf16_hi(u) : bf16_lo(u);
        }
    }
}

// ---------------- Fallback (no workspace): direct NCHW kernel ----------------
__global__ __launch_bounds__(256) void roialign_fwd(
    const float* __restrict__ feat,
    const float* __restrict__ rois,
    const int* __restrict__ roibatches,
    float* __restrict__ out,
    int total)
{
    int tid = blockIdx.x * blockDim.x + threadIdx.x;
    if (tid >= total) return;
    int n   = tid / (Cc * POOL * POOL);
    int rem = tid % (Cc * POOL * POOL);
    int c   = rem / (POOL * POOL);
    int bin = rem % (POOL * POOL);
    int ph  = bin / POOL;
    int pw  = bin % POOL;

    float x1 = rois[n * 4 + 0] * SCALEc;
    float y1 = rois[n * 4 + 1] * SCALEc;
    float x2 = rois[n * 4 + 2] * SCALEc;
    float y2 = rois[n * 4 + 3] * SCALEc;
    int   b  = roibatches[n];

    float roi_w = fmaxf(x2 - x1, 1.0f);
    float roi_h = fmaxf(y2 - y1, 1.0f);
    float bin_w = roi_w * (1.0f / POOL);
    float bin_h = roi_h * (1.0f / POOL);

    const float* fp = feat + (size_t)(b * Cc + c) * (size_t)HWc;

    float acc = 0.0f;
#pragma unroll
    for (int iy = 0; iy < 2; ++iy) {
        float y  = y1 + ((float)ph + ((float)iy + 0.5f) * 0.5f) * bin_h;
        bool  vy = (y >= -1.0f) && (y <= (float)Hc);
        float yc = fminf(fmaxf(y, 0.0f), (float)(Hc - 1));
        int   y_lo = (int)floorf(yc);
        int   y_hi = min(y_lo + 1, Hc - 1);
        float ly = yc - (float)y_lo;
        float hy = 1.0f - ly;
        float wyl = vy ? hy : 0.0f;
        float wyh = vy ? ly : 0.0f;
        const float* row_lo = fp + (size_t)y_lo * Wc;
        const float* row_hi = fp + (size_t)y_hi * Wc;
#pragma unroll
        for (int ix = 0; ix < 2; ++ix) {
            float x  = x1 + ((float)pw + ((float)ix + 0.5f) * 0.5f) * bin_w;
            bool  vx = (x >= -1.0f) && (x <= (float)Wc);
            float xc = fminf(fmaxf(x, 0.0f), (float)(Wc - 1));
            int   x_lo = (int)floorf(xc);
            int   x_hi = min(x_lo + 1, Wc - 1);
            float lx = xc - (float)x_lo;
            float hx = 1.0f - lx;
            float wxl = vx ? hx : 0.0f;
            float wxh = vx ? lx : 0.0f;
            acc += wyl * (wxl * row_lo[x_lo] + wxh * row_lo[x_hi])
                 + wyh * (wxl * row_hi[x_lo] + wxh * row_hi[x_hi]);
        }
    }
    out[tid] = acc * 0.25f;
}

extern "C" void kernel_launch(void* const* d_in, const int* in_sizes, int n_in,
                              void* d_out, int out_size, void* d_ws, size_t ws_size,
                              hipStream_t stream)
{
    const float* feat       = (const float*)d_in[0];
    const float* rois       = (const float*)d_in[1];
    const int*   roibatches = (const int*)d_in[2];
    float*       out        = (float*)d_out;
    int N = in_sizes[1] / 4;

    size_t need_nhwc = (size_t)Bc * HWc * Cc * sizeof(ushort);  // ~124.5 MB
    size_t need = need_nhwc + (size_t)N * sizeof(int);
    if (ws_size >= need && N <= 1024) {
        ushort* fbh  = (ushort*)d_ws;
        int*    perm = (int*)((char*)d_ws + need_nhwc);

        sort_rois<<<1, 1024, 0, stream>>>(rois, roibatches, perm, N);

        dim3 tgrid(HWc / 64, Cc / 128, Bc);
        dim3 tblock(64, 4);
        nchw_to_nhwc_bf16<<<tgrid, tblock, 0, stream>>>(feat, fbh);

        roialign_gather<<<N, 512, 0, stream>>>(fbh, rois, roibatches, perm, out);
    } else {
        int total = out_size;
        roialign_fwd<<<(total + 255) / 256, 256, 0, stream>>>(
            feat, rois, roibatches, out, total);
    }
}

// Round 9
// 121.088 us; speedup vs baseline: 1.1141x; 1.1141x over previous
//
#include <hip/hip_runtime.h>
#include <hip/hip_bf16.h>

// ROIAlign: feat [B=4, C=256, H=200, W=304] fp32, rois [N=1024,4] fp32,
// roibatches [N] int32 -> out [N, C, 7, 7] fp32.  POOL=7, SCALE=0.25, SAMP=2.
//
// K0: stable counting sort of roi ids by batch -> perm.
// K1: NCHW fp32 -> [B][8cg][H][W][32ch] bf16 in d_ws (124 MB).
// K2: grid = rank*8+cg, cg = bid&7 -> XCD k only touches channel-group k
//     (3.9 MB/batch slice, L2-resident => inter-roi reuse served by L2).
//     Block (512thr) = one (roi, cg): wave = 8 bins (lane-octet each),
//     lane owns 4ch (uint2 corner loads; 8x64B = 512B/instr, full lines).

#define POOL 7
constexpr int Bc = 4;
constexpr int Cc = 256;
constexpr int Hc = 200;
constexpr int Wc = 304;
constexpr int HWc = Hc * Wc;           // 60800
constexpr float SCALEc = 0.25f;

static __device__ __forceinline__ float bf16_lo(unsigned u) {
    u <<= 16;
    return __builtin_bit_cast(float, u);
}
static __device__ __forceinline__ float bf16_hi(unsigned u) {
    u &= 0xFFFF0000u;
    return __builtin_bit_cast(float, u);
}
static __device__ __forceinline__ unsigned pack_bf16(float f0, float f1) {
    unsigned u0 = (unsigned)__hip_bfloat16_raw(__float2bfloat16(f0)).x;
    unsigned u1 = (unsigned)__hip_bfloat16_raw(__float2bfloat16(f1)).x;
    return u0 | (u1 << 16);
}

// ---------------- K0: stable counting sort of roi ids by batch ----------------
__global__ __launch_bounds__(1024) void sort_rois_by_batch(
    const int* __restrict__ rb, int* __restrict__ perm, int N)
{
    __shared__ int wave_cnt[16][4];
    __shared__ int bucket_base[4];
    int t    = threadIdx.x;
    int w    = t >> 6;
    int lane = t & 63;
    int b    = (t < N) ? rb[t] : -1;

    unsigned long long m[4];
#pragma unroll
    for (int k = 0; k < 4; ++k) m[k] = __ballot(b == k);
    if (lane == 0) {
#pragma unroll
        for (int k = 0; k < 4; ++k) wave_cnt[w][k] = __popcll(m[k]);
    }
    __syncthreads();
    if (t == 0) {
        int base = 0;
#pragma unroll
        for (int k = 0; k < 4; ++k) {
            int tot = 0;
            for (int ww = 0; ww < 16; ++ww) tot += wave_cnt[ww][k];
            bucket_base[k] = base;
            base += tot;
        }
    }
    __syncthreads();
    if (b >= 0) {
        int rank = bucket_base[b];
        for (int ww = 0; ww < w; ++ww) rank += wave_cnt[ww][b];
        unsigned long long lt = (lane == 0) ? 0ULL : (~0ULL >> (64 - lane));
        rank += __popcll(m[b] & lt);
        perm[rank] = t;
    }
}

// ---------------- K1: NCHW fp32 -> [B][8][HW][32] bf16 ----------------
// Tile: 128 channels x 64 HW positions. Block (64,4).
__global__ __launch_bounds__(256) void nchw_to_cg32_bf16(
    const float* __restrict__ in, ushort* __restrict__ outp)
{
    __shared__ float tile[128][65];
    int b  = blockIdx.z;
    int p0 = blockIdx.x * 64;    // HW origin
    int c0 = blockIdx.y * 128;   // C origin (0 or 128)
    int tx = threadIdx.x;        // 0..63
    int ty = threadIdx.y;        // 0..3

    const float* src = in + ((size_t)b * Cc + c0) * (size_t)HWc + p0;
#pragma unroll
    for (int k = 0; k < 32; ++k) {
        int c = ty + 4 * k;
        tile[c][tx ^ ((c >> 5) & 3)] = src[(size_t)c * HWc + tx];
    }
    __syncthreads();

    int t   = ty * 64 + tx;      // 0..255
    int ch8 = (t & 3) * 8;       // 0,8,16,24 within the 32-ch group
    int p   = t >> 2;            // 0..63
#pragma unroll
    for (int cgl = 0; cgl < 4; ++cgl) {
        int cg = (c0 >> 5) + cgl;           // 0..7
        unsigned u[4];
#pragma unroll
        for (int j = 0; j < 4; ++j) {
            int ce = cgl * 32 + ch8 + 2 * j;
            int co = ce + 1;
            float f0 = tile[ce][p ^ ((ce >> 5) & 3)];
            float f1 = tile[co][p ^ ((co >> 5) & 3)];
            u[j] = pack_bf16(f0, f1);
        }
        size_t d = ((size_t)(b * 8 + cg) * HWc + p0 + p) * 32 + ch8;
        *(uint4*)(outp + d) = make_uint4(u[0], u[1], u[2], u[3]);
    }
}

// ---------------- K2: gather + pool, block = (roi rank, cgroup) ----------------
__global__ __launch_bounds__(512, 8) void roialign_gather_cg(
    const ushort* __restrict__ f,      // [B][8][HW][32] bf16
    const float*  __restrict__ rois,
    const int*    __restrict__ rb,
    const int*    __restrict__ perm,
    float*        __restrict__ out)
{
    __shared__ float stage[32 * 50];   // [ch][bin], row stride 50

    int bid  = blockIdx.x;
    int cg   = bid & 7;            // == XCD (round-robin dispatch)
    int r    = bid >> 3;           // sorted rank
    int n    = perm[r];
    int t    = threadIdx.x;        // 0..511
    int w    = t >> 6;             // wave 0..7
    int lane = t & 63;
    int oct  = lane >> 3;          // 0..7 -> bin = w*8 + oct
    int cs   = lane & 7;           // uint2 slot: channels cs*4 .. cs*4+3
    int bin  = w * 8 + oct;        // 0..63

    float x1 = rois[n * 4 + 0] * SCALEc;
    float y1 = rois[n * 4 + 1] * SCALEc;
    float x2 = rois[n * 4 + 2] * SCALEc;
    float y2 = rois[n * 4 + 3] * SCALEc;
    int   b  = rb[n];

    float roi_w = fmaxf(x2 - x1, 1.0f);
    float roi_h = fmaxf(y2 - y1, 1.0f);
    float bin_w = roi_w * (1.0f / POOL);
    float bin_h = roi_h * (1.0f / POOL);

    // cg slice base; one pixel = 8 uint2 (32 bf16 ch)
    const uint2* fb = (const uint2*)(f + (size_t)(b * 8 + cg) * ((size_t)HWc * 32));

    if (bin < 49) {
        int ph = (bin * 9363) >> 16;   // bin / 7
        int pw = bin - ph * 7;

        unsigned yrow[2][2];  float wy[2][2];
#pragma unroll
        for (int iy = 0; iy < 2; ++iy) {
            float y  = y1 + ((float)ph + ((float)iy + 0.5f) * 0.5f) * bin_h;
            bool  vy = (y >= -1.0f) && (y <= (float)Hc);
            float yc = fminf(fmaxf(y, 0.0f), (float)(Hc - 1));
            int   y_lo = (int)floorf(yc);
            int   y_hi = min(y_lo + 1, Hc - 1);
            float ly = yc - (float)y_lo;
            yrow[iy][0] = (unsigned)(y_lo * Wc);
            yrow[iy][1] = (unsigned)(y_hi * Wc);
            wy[iy][0] = vy ? (1.0f - ly) : 0.0f;
            wy[iy][1] = vy ? ly : 0.0f;
        }
        unsigned xo[2][2];  float wx[2][2];
#pragma unroll
        for (int ix = 0; ix < 2; ++ix) {
            float x  = x1 + ((float)pw + ((float)ix + 0.5f) * 0.5f) * bin_w;
            bool  vx = (x >= -1.0f) && (x <= (float)Wc);
            float xc = fminf(fmaxf(x, 0.0f), (float)(Wc - 1));
            int   x_lo = (int)floorf(xc);
            int   x_hi = min(x_lo + 1, Wc - 1);
            float lx = xc - (float)x_lo;
            xo[ix][0] = (unsigned)x_lo;
            xo[ix][1] = (unsigned)x_hi;
            wx[ix][0] = vx ? (1.0f - lx) : 0.0f;
            wx[ix][1] = vx ? lx : 0.0f;
        }

        float acc0 = 0.f, acc1 = 0.f, acc2 = 0.f, acc3 = 0.f;
#pragma unroll
        for (int iy = 0; iy < 2; ++iy) {
            // batch this y-sample's 8 corner loads (uint2 each, 64B/pixel lines)
            uint2 v[8];
#pragma unroll
            for (int q = 0; q < 8; ++q) {
                int yl = q >> 2, ix = (q >> 1) & 1, xl = q & 1;
                unsigned pix = yrow[iy][yl] + xo[ix][xl];
                v[q] = fb[(size_t)pix * 8u + (unsigned)cs];
            }
#pragma unroll
            for (int q = 0; q < 8; ++q) {
                int yl = q >> 2, ix = (q >> 1) & 1, xl = q & 1;
                float wq = wy[iy][yl] * wx[ix][xl];
                acc0 = fmaf(wq, bf16_lo(v[q].x), acc0);
                acc1 = fmaf(wq, bf16_hi(v[q].x), acc1);
                acc2 = fmaf(wq, bf16_lo(v[q].y), acc2);
                acc3 = fmaf(wq, bf16_hi(v[q].y), acc3);
            }
        }
        int ch = cs * 4;
        stage[(ch + 0) * 50 + bin] = acc0 * 0.25f;
        stage[(ch + 1) * 50 + bin] = acc1 * 0.25f;
        stage[(ch + 2) * 50 + bin] = acc2 * 0.25f;
        stage[(ch + 3) * 50 + bin] = acc3 * 0.25f;
    }
    __syncthreads();

    // coalesced write of this (roi, cg) 1568-float contiguous chunk
    float* obase = out + (size_t)n * (Cc * POOL * POOL) + (size_t)cg * (32 * POOL * POOL);
#pragma unroll
    for (int k = 0; k < 4; ++k) {
        int flat = t + 512 * k;            // c*49 + bin, c in [0,32)
        if (flat < 32 * POOL * POOL) {
            unsigned c    = ((unsigned)flat * 42800u) >> 21;   // flat / 49
            unsigned bn   = (unsigned)flat - c * 49u;
            obase[flat] = stage[c * 50 + bn];
        }
    }
}

// ---------------- Fallback (no workspace): direct NCHW kernel ----------------
__global__ __launch_bounds__(256) void roialign_fwd(
    const float* __restrict__ feat,
    const float* __restrict__ rois,
    const int* __restrict__ roibatches,
    float* __restrict__ out,
    int total)
{
    int tid = blockIdx.x * blockDim.x + threadIdx.x;
    if (tid >= total) return;
    int n   = tid / (Cc * POOL * POOL);
    int rem = tid % (Cc * POOL * POOL);
    int c   = rem / (POOL * POOL);
    int bin = rem % (POOL * POOL);
    int ph  = bin / POOL;
    int pw  = bin % POOL;

    float x1 = rois[n * 4 + 0] * SCALEc;
    float y1 = rois[n * 4 + 1] * SCALEc;
    float x2 = rois[n * 4 + 2] * SCALEc;
    float y2 = rois[n * 4 + 3] * SCALEc;
    int   b  = roibatches[n];

    float roi_w = fmaxf(x2 - x1, 1.0f);
    float roi_h = fmaxf(y2 - y1, 1.0f);
    float bin_w = roi_w * (1.0f / POOL);
    float bin_h = roi_h * (1.0f / POOL);

    const float* fp = feat + (size_t)(b * Cc + c) * (size_t)HWc;

    float acc = 0.0f;
#pragma unroll
    for (int iy = 0; iy < 2; ++iy) {
        float y  = y1 + ((float)ph + ((float)iy + 0.5f) * 0.5f) * bin_h;
        bool  vy = (y >= -1.0f) && (y <= (float)Hc);
        float yc = fminf(fmaxf(y, 0.0f), (float)(Hc - 1));
        int   y_lo = (int)floorf(yc);
        int   y_hi = min(y_lo + 1, Hc - 1);
        float ly = yc - (float)y_lo;
        float hy = 1.0f - ly;
        float wyl = vy ? hy : 0.0f;
        float wyh = vy ? ly : 0.0f;
        const float* row_lo = fp + (size_t)y_lo * Wc;
        const float* row_hi = fp + (size_t)y_hi * Wc;
#pragma unroll
        for (int ix = 0; ix < 2; ++ix) {
            float x  = x1 + ((float)pw + ((float)ix + 0.5f) * 0.5f) * bin_w;
            bool  vx = (x >= -1.0f) && (x <= (float)Wc);
            float xc = fminf(fmaxf(x, 0.0f), (float)(Wc - 1));
            int   x_lo = (int)floorf(xc);
            int   x_hi = min(x_lo + 1, Wc - 1);
            float lx = xc - (float)x_lo;
            float hx = 1.0f - lx;
            float wxl = vx ? hx : 0.0f;
            float wxh = vx ? lx : 0.0f;
            acc += wyl * (wxl * row_lo[x_lo] + wxh * row_lo[x_hi])
                 + wyh * (wxl * row_hi[x_lo] + wxh * row_hi[x_hi]);
        }
    }
    out[tid] = acc * 0.25f;
}

extern "C" void kernel_launch(void* const* d_in, const int* in_sizes, int n_in,
                              void* d_out, int out_size, void* d_ws, size_t ws_size,
                              hipStream_t stream)
{
    const float* feat       = (const float*)d_in[0];
    const float* rois       = (const float*)d_in[1];
    const int*   roibatches = (const int*)d_in[2];
    float*       out        = (float*)d_out;
    int N = in_sizes[1] / 4;

    size_t need_copy = (size_t)Bc * HWc * Cc * sizeof(ushort);  // ~124.5 MB
    size_t need = need_copy + (size_t)N * sizeof(int);
    if (ws_size >= need && N <= 1024) {
        ushort* fbh  = (ushort*)d_ws;
        int*    perm = (int*)((char*)d_ws + need_copy);

        sort_rois_by_batch<<<1, 1024, 0, stream>>>(roibatches, perm, N);

        dim3 tgrid(HWc / 64, Cc / 128, Bc);
        dim3 tblock(64, 4);
        nchw_to_cg32_bf16<<<tgrid, tblock, 0, stream>>>(feat, fbh);

        roialign_gather_cg<<<N * 8, 512, 0, stream>>>(fbh, rois, roibatches, perm, out);
    } else {
        int total = out_size;
        roialign_fwd<<<(total + 255) / 256, 256, 0, stream>>>(
            feat, rois, roibatches, out, total);
    }
}